// Round 1
// baseline (36660.855 us; speedup 1.0000x reference)
//
#include <hip/hip_runtime.h>
#include <math.h>

// Problem constants
constexpr int Bb = 64, Tt = 500, Ee = 256, Gg = 256, Aa = 128, Dd = 400;
constexpr int H1 = 256, H2 = 128, STEPS = 500, Rr = 5;

// ---------------------------------------------------------------------------
// Pre-kernel: enc_proj[b,t,a] = sum_k enc_feat[b,t,k] * W_enc[k,a]
// grid (64, 32), 512 threads; block handles (b, 16 consecutive t)
// ---------------------------------------------------------------------------
__global__ __launch_bounds__(512)
void k_encproj(const float* __restrict__ enc_feat,
               const float* __restrict__ W_enc,
               float* __restrict__ enc_proj) {
  __shared__ float sFeat[16][256];
  const int b = blockIdx.x, tg = blockIdx.y;
  const int t0 = tg * 16;
  const int tid = threadIdx.x;

  #pragma unroll
  for (int i = 0; i < 8; ++i) {
    int idx = tid + i * 512;
    int r = idx >> 8, c = idx & 255;
    int t = t0 + r;
    sFeat[r][c] = (t < Tt) ? enc_feat[((size_t)b * Tt + t) * Ee + c] : 0.0f;
  }
  __syncthreads();

  const int a = tid & 127, tl = tid >> 7;  // tl in 0..3, handles rows tl,tl+4,tl+8,tl+12
  float acc0 = 0.f, acc1 = 0.f, acc2 = 0.f, acc3 = 0.f;
  #pragma unroll 4
  for (int k = 0; k < Ee; ++k) {
    float w = W_enc[k * Aa + a];
    acc0 = fmaf(sFeat[tl][k],      w, acc0);
    acc1 = fmaf(sFeat[tl + 4][k],  w, acc1);
    acc2 = fmaf(sFeat[tl + 8][k],  w, acc2);
    acc3 = fmaf(sFeat[tl + 12][k], w, acc3);
  }
  float accs[4] = {acc0, acc1, acc2, acc3};
  #pragma unroll
  for (int i = 0; i < 4; ++i) {
    int t = t0 + tl + 4 * i;
    if (t < Tt) enc_proj[((size_t)b * Tt + t) * Aa + a] = accs[i];
  }
}

// ---------------------------------------------------------------------------
// Helpers for the persistent decoder kernel
// ---------------------------------------------------------------------------

// Partial GEMV: y = x[K] * W[K x ldW] restricted to 4*QUADS output columns
// (W pre-offset to the column block). 512 threads = (QUADS output quads) x
// (512/QUADS k-slices of length KS). Per-thread float4 partial into sTmp.
template<int QUADS, int KS>
__device__ __forceinline__ void gemv_partial(const float* __restrict__ W, const int ldW,
                                             const float* __restrict__ xl,
                                             float* __restrict__ sTmp, int tid) {
  const int q = tid & (QUADS - 1);
  const int s = tid / QUADS;
  const float* Wp = W + 4 * q + (size_t)(s * KS) * ldW;
  const float* xp = xl + s * KS;
  float4 acc = {0.f, 0.f, 0.f, 0.f};
  #pragma unroll 4
  for (int k = 0; k < KS; ++k) {
    float xv = xp[k];
    float4 w = *(const float4*)(Wp + (size_t)k * ldW);
    acc.x = fmaf(xv, w.x, acc.x);
    acc.y = fmaf(xv, w.y, acc.y);
    acc.z = fmaf(xv, w.z, acc.z);
    acc.w = fmaf(xv, w.w, acc.w);
  }
  *(float4*)&sTmp[tid * 4] = acc;
}

template<int QUADS, int NSL>
__device__ __forceinline__ float combine(const float* __restrict__ sTmp, int j) {
  float v = 0.f;
  #pragma unroll
  for (int s = 0; s < NSL; ++s)
    v += sTmp[(s * QUADS + (j >> 2)) * 4 + (j & 3)];
  return v;
}

__device__ __forceinline__ float sigmoid_acc(float x) {
  // exp handles inf cleanly: x->-inf => e=inf => 0 ; x->+inf => e=0 => 1
  float e = __expf(-x);
  return 1.0f / (1.0f + e);
}

__device__ __forceinline__ float tanh_acc(float x) {
  float cx = fminf(9.5f, fmaxf(-9.5f, x));   // tanh(9.5) = 1 - 1e-8
  float e = __expf(2.0f * cx);
  return (e - 1.0f) / (e + 1.0f);
}

__device__ __forceinline__ float tanh_fast(float x) {   // hot path (64K/step/row)
  float cx = fminf(9.5f, fmaxf(-9.5f, x));
  float e = __expf(2.0f * cx);
  return (e - 1.0f) * __builtin_amdgcn_rcpf(e + 1.0f);  // v_rcp_f32, ~1ulp
}

// ---------------------------------------------------------------------------
// Main persistent kernel: one block per batch row, 500 steps, state in LDS.
// ---------------------------------------------------------------------------
__global__ __launch_bounds__(512, 1)
void k_decoder(const float* __restrict__ enc_feat,
               const float* __restrict__ enc_proj,
               const float* __restrict__ W_p1, const float* __restrict__ b_p1,
               const float* __restrict__ W_p2, const float* __restrict__ b_p2,
               const float* __restrict__ W_ix, const float* __restrict__ W_ih,
               const float* __restrict__ b_ix, const float* __restrict__ b_ih,
               const float* __restrict__ W_dec, const float* __restrict__ b_attn,
               const float* __restrict__ v_attn,
               const float* __restrict__ W_out, const float* __restrict__ b_out,
               float* __restrict__ pred_out, float* __restrict__ attn_out) {
  __shared__ __align__(16) float sPred[400];
  __shared__ __align__(16) float sIn[384];    // [x(128) | ctx(256)] : GRU input
  __shared__ __align__(16) float sL1[256];
  __shared__ __align__(16) float sCat[512];   // [h(256) | ctx(256)] : W_out input
  __shared__ __align__(16) float sR[256];
  __shared__ __align__(16) float sZ[256];
  __shared__ __align__(16) float sSd[128];
  __shared__ __align__(16) float sScore[512];
  __shared__ __align__(16) float sRaw[400];
  __shared__ __align__(16) float sTmpA[2048]; // float4[512]
  __shared__ __align__(16) float sTmpB[2048];
  __shared__ float sRed[8];

  float* sH   = sCat;        // h lives in sCat[0:256]
  float* sCtx = sCat + 256;  // ctx in sCat[256:512]

  const int b = blockIdx.x;
  const int tid = threadIdx.x;
  const int lane = tid & 63, wid = tid >> 6;
  const int l4 = tid & 3;

  // init state: pred = h = ctx = 0
  for (int i = tid; i < 400; i += 512) sPred[i] = 0.f;
  for (int i = tid; i < 256; i += 512) { sH[i] = 0.f; sCtx[i] = 0.f; sIn[128 + i] = 0.f; }
  __syncthreads();

  // preload v_attn quads for the score pass (constant across steps)
  float4 vq[8];
  #pragma unroll
  for (int i = 0; i < 8; ++i) vq[i] = *(const float4*)(v_attn + 4 * (l4 + 4 * i));

  for (int t = 0; t < STEPS; ++t) {
    // ---- P1: l1 = relu(pred @ W_p1 + b_p1)   [K=400, N=256]
    gemv_partial<64, 50>(W_p1, 256, sPred, sTmpA, tid);
    __syncthreads();
    if (tid < 256) {
      float v = b_p1[tid] + combine<64, 8>(sTmpA, tid);
      sL1[tid] = fmaxf(v, 0.f);
    }
    __syncthreads();

    // ---- P2: x = relu(l1 @ W_p2 + b_p2)      [K=256, N=128] -> sIn[0:128]
    gemv_partial<32, 16>(W_p2, 128, sL1, sTmpA, tid);
    __syncthreads();
    if (tid < 128) {
      float v = b_p2[tid] + combine<32, 16>(sTmpA, tid);
      sIn[tid] = fmaxf(v, 0.f);
    }
    __syncthreads();

    // ---- P3: r = sigmoid(i_r + h_r)
    gemv_partial<64, 48>(W_ix, 768, sIn, sTmpA, tid);       // K=384
    gemv_partial<64, 32>(W_ih, 768, sH, sTmpB, tid);        // K=256
    __syncthreads();
    if (tid < 256) {
      float ir = b_ix[tid] + combine<64, 8>(sTmpA, tid);
      float hr = b_ih[tid] + combine<64, 8>(sTmpB, tid);
      sR[tid] = sigmoid_acc(ir + hr);
    }
    __syncthreads();

    // ---- P4: z = sigmoid(i_z + h_z)
    gemv_partial<64, 48>(W_ix + 256, 768, sIn, sTmpA, tid);
    gemv_partial<64, 32>(W_ih + 256, 768, sH, sTmpB, tid);
    __syncthreads();
    if (tid < 256) {
      float iz = b_ix[256 + tid] + combine<64, 8>(sTmpA, tid);
      float hz = b_ih[256 + tid] + combine<64, 8>(sTmpB, tid);
      sZ[tid] = sigmoid_acc(iz + hz);
    }
    __syncthreads();

    // ---- P5: n = tanh(i_n + r*h_n); h = (1-z)*n + z*h   (in-place h update)
    gemv_partial<64, 48>(W_ix + 512, 768, sIn, sTmpA, tid);
    gemv_partial<64, 32>(W_ih + 512, 768, sH, sTmpB, tid);
    __syncthreads();
    if (tid < 256) {
      float in_ = b_ix[512 + tid] + combine<64, 8>(sTmpA, tid);
      float hn_ = b_ih[512 + tid] + combine<64, 8>(sTmpB, tid);
      float n = tanh_acc(in_ + sR[tid] * hn_);
      float z = sZ[tid];
      sH[tid] = (1.f - z) * n + z * sH[tid];
    }
    __syncthreads();

    // ---- P6: s_dec = h @ W_dec + b_attn      [K=256, N=128]
    gemv_partial<32, 16>(W_dec, 128, sH, sTmpA, tid);
    __syncthreads();
    if (tid < 128) sSd[tid] = b_attn[tid] + combine<32, 16>(sTmpA, tid);
    __syncthreads();

    // ---- P7: scores[t'] = sum_a v[a]*tanh(enc_proj[b,t',a] + s_dec[a])
    {
      float4 sdq[8];
      #pragma unroll
      for (int i = 0; i < 8; ++i) sdq[i] = *(const float4*)(sSd + 4 * (l4 + 4 * i));
      const int g = tid >> 2;
      #pragma unroll
      for (int p = 0; p < 4; ++p) {
        int tt = g + (p << 7);
        float acc = 0.f;
        if (tt < Tt) {
          const float4* ep = (const float4*)(enc_proj + ((size_t)b * Tt + tt) * Aa);
          #pragma unroll
          for (int i = 0; i < 8; ++i) {
            float4 e4 = ep[l4 + 4 * i];
            acc = fmaf(vq[i].x, tanh_fast(e4.x + sdq[i].x), acc);
            acc = fmaf(vq[i].y, tanh_fast(e4.y + sdq[i].y), acc);
            acc = fmaf(vq[i].z, tanh_fast(e4.z + sdq[i].z), acc);
            acc = fmaf(vq[i].w, tanh_fast(e4.w + sdq[i].w), acc);
          }
        }
        acc += __shfl_xor(acc, 1);
        acc += __shfl_xor(acc, 2);
        if (l4 == 0 && tt < Tt) sScore[tt] = acc;
      }
      __syncthreads();
    }

    // ---- P8: softmax over T; write attn record; keep attn in sScore
    {
      float val = (tid < Tt) ? sScore[tid] : -3.0e38f;
      float m = val;
      #pragma unroll
      for (int off = 32; off >= 1; off >>= 1) m = fmaxf(m, __shfl_xor(m, off));
      if (lane == 0) sRed[wid] = m;
      __syncthreads();
      float bm = sRed[0];
      #pragma unroll
      for (int w = 1; w < 8; ++w) bm = fmaxf(bm, sRed[w]);
      float e = (tid < Tt) ? __expf(val - bm) : 0.f;
      float ssum = e;
      #pragma unroll
      for (int off = 32; off >= 1; off >>= 1) ssum += __shfl_xor(ssum, off);
      __syncthreads();                 // all reads of sRed (max) done
      if (lane == 0) sRed[wid] = ssum;
      __syncthreads();
      float S = 0.f;
      #pragma unroll
      for (int w = 0; w < 8; ++w) S += sRed[w];
      if (tid < Tt) {
        float attn = e / S;
        sScore[tid] = attn;
        attn_out[((size_t)b * STEPS + t) * Tt + tid] = attn;
      }
      __syncthreads();
    }

    // ---- P9: ctx[e] = sum_t' attn[t'] * enc_feat[b,t',e]   -> sCtx, sIn[128:]
    {
      const int e4i = tid & 63, sl = tid >> 6;
      const int t0s = sl * 63;
      const int t1s = (t0s + 63 < Tt) ? (t0s + 63) : Tt;  // 7*63=441, last 59
      float4 acc = {0.f, 0.f, 0.f, 0.f};
      const float* fb = enc_feat + (size_t)b * Tt * Ee + 4 * e4i;
      #pragma unroll 4
      for (int tt = t0s; tt < t1s; ++tt) {
        float a = sScore[tt];
        float4 f = *(const float4*)(fb + (size_t)tt * Ee);
        acc.x = fmaf(a, f.x, acc.x);
        acc.y = fmaf(a, f.y, acc.y);
        acc.z = fmaf(a, f.z, acc.z);
        acc.w = fmaf(a, f.w, acc.w);
      }
      *(float4*)&sTmpA[tid * 4] = acc;
      __syncthreads();
      if (tid < 256) {
        float v = combine<64, 8>(sTmpA, tid);
        sCtx[tid] = v;
        sIn[128 + tid] = v;
      }
      __syncthreads();
    }

    // ---- P10: raw = [h,ctx] @ W_out + b_out  [K=512, N=400]
    {
      if (tid < 500) {
        const int s = tid / 100;
        const int q = tid - s * 100;
        const int k0 = s * 103;
        const int k1 = (s == 4) ? 512 : k0 + 103;
        const float* Wp = W_out + 4 * q;
        float4 acc = {0.f, 0.f, 0.f, 0.f};
        for (int k = k0; k < k1; ++k) {
          float xv = sCat[k];
          float4 w = *(const float4*)(Wp + (size_t)k * 400);
          acc.x = fmaf(xv, w.x, acc.x);
          acc.y = fmaf(xv, w.y, acc.y);
          acc.z = fmaf(xv, w.z, acc.z);
          acc.w = fmaf(xv, w.w, acc.w);
        }
        *(float4*)&sTmpA[tid * 4] = acc;
      }
      __syncthreads();
      if (tid < 400) {
        float v = b_out[tid];
        #pragma unroll
        for (int s2 = 0; s2 < 5; ++s2)
          v += sTmpA[(s2 * 100 + (tid >> 2)) * 4 + (tid & 3)];
        sRaw[tid] = v;
      }
      __syncthreads();
    }

    // ---- P11: pred = chunked softmax(raw, 5 x 80); write pred record
    {
      if (wid < Rr) {
        int d0 = wid * 80 + lane;
        float v0 = sRaw[d0];
        float v1 = (lane < 16) ? sRaw[d0 + 64] : -3.0e38f;
        float m = fmaxf(v0, v1);
        #pragma unroll
        for (int off = 32; off >= 1; off >>= 1) m = fmaxf(m, __shfl_xor(m, off));
        float e0 = __expf(v0 - m);
        float e1 = (lane < 16) ? __expf(v1 - m) : 0.f;
        float s = e0 + e1;
        #pragma unroll
        for (int off = 32; off >= 1; off >>= 1) s += __shfl_xor(s, off);
        float inv = 1.0f / s;
        float p0 = e0 * inv;
        sPred[d0] = p0;
        pred_out[((size_t)b * STEPS + t) * Dd + d0] = p0;
        if (lane < 16) {
          float p1 = e1 * inv;
          sPred[d0 + 64] = p1;
          pred_out[((size_t)b * STEPS + t) * Dd + d0 + 64] = p1;
        }
      }
      __syncthreads();
    }
  }
}

// ---------------------------------------------------------------------------
extern "C" void kernel_launch(void* const* d_in, const int* in_sizes, int n_in,
                              void* d_out, int out_size, void* d_ws, size_t ws_size,
                              hipStream_t stream) {
  const float* enc_feat = (const float*)d_in[0];
  const float* W_p1  = (const float*)d_in[1];
  const float* b_p1  = (const float*)d_in[2];
  const float* W_p2  = (const float*)d_in[3];
  const float* b_p2  = (const float*)d_in[4];
  const float* W_ix  = (const float*)d_in[5];
  const float* W_ih  = (const float*)d_in[6];
  const float* b_ix  = (const float*)d_in[7];
  const float* b_ih  = (const float*)d_in[8];
  const float* W_dec = (const float*)d_in[9];
  const float* W_enc = (const float*)d_in[10];
  const float* b_attn= (const float*)d_in[11];
  const float* v_attn= (const float*)d_in[12];
  const float* W_out = (const float*)d_in[13];
  const float* b_out = (const float*)d_in[14];

  float* pred_out = (float*)d_out;                              // [64,500,400]
  float* attn_out = pred_out + (size_t)Bb * STEPS * Dd;         // [64,500,500]
  float* enc_proj = (float*)d_ws;                               // [64,500,128] = 16.4 MB

  k_encproj<<<dim3(Bb, 32), 512, 0, stream>>>(enc_feat, W_enc, enc_proj);
  k_decoder<<<Bb, 512, 0, stream>>>(enc_feat, enc_proj,
                                    W_p1, b_p1, W_p2, b_p2,
                                    W_ix, W_ih, b_ix, b_ih,
                                    W_dec, b_attn, v_attn, W_out, b_out,
                                    pred_out, attn_out);
}